// Round 3
// baseline (801.141 us; speedup 1.0000x reference)
//
#include <hip/hip_runtime.h>
#include <math.h>

// (B, L, E, H) = (4, 1024, 2048, 16), DH = 128
#define BB 4
#define LL 1024
#define EE 2048
#define HH 16
#define DHD 128
#define NTOK 4096
#define NBH 64
#define OUT0_ELEMS 8388608     // B*L*E

typedef __attribute__((ext_vector_type(8))) short short8;       // 8 bf16 (MFMA A/B frag)
typedef __attribute__((ext_vector_type(4))) float f32x4;        // MFMA C/D frag
typedef __attribute__((ext_vector_type(4))) unsigned short ushort4v;
typedef __attribute__((ext_vector_type(8))) unsigned short ushort8v;

__device__ __forceinline__ unsigned short f2bf(float x) {
    union { float f; unsigned int u; } v; v.f = x;
    unsigned int r = v.u + 0x7FFFu + ((v.u >> 16) & 1u);   // RNE
    return (unsigned short)(r >> 16);
}
__device__ __forceinline__ float bf2f(unsigned short h) {
    union { unsigned int u; float f; } v; v.u = ((unsigned int)h) << 16;
    return v.f;
}

// async global->LDS, 16B per lane
__device__ __forceinline__ void gload16(const void* g, void* l) {
    __builtin_amdgcn_global_load_lds((const __attribute__((address_space(1))) void*)g,
                                     (__attribute__((address_space(3))) void*)l,
                                     16, 0, 0);
}

// ---------------------------------------------------------------------------
// fp32 -> bf16 bulk convert
// ---------------------------------------------------------------------------
__global__ __launch_bounds__(256) void cvt_k(const float* __restrict__ in,
                                             unsigned short* __restrict__ out, int n) {
    int i = (blockIdx.x * 256 + threadIdx.x) * 8;
    if (i >= n) return;
    float4 a = *(const float4*)(in + i);
    float4 b = *(const float4*)(in + i + 4);
    ushort4v u, w;
    u.x = f2bf(a.x); u.y = f2bf(a.y); u.z = f2bf(a.z); u.w = f2bf(a.w);
    w.x = f2bf(b.x); w.y = f2bf(b.y); w.z = f2bf(b.z); w.w = f2bf(b.w);
    *(ushort4v*)(out + i) = u;
    *(ushort4v*)(out + i + 4) = w;
}

// ---------------------------------------------------------------------------
// xPos table
// ---------------------------------------------------------------------------
__global__ __launch_bounds__(64) void xpos_table_k(float4* __restrict__ tab) {
    int t = blockIdx.x;
    int j = threadIdx.x;
    float pos = (float)(t - 512);
    float base = (2.0f * (float)j + 51.2f) * (1.0f / 179.2f);
    float sc = powf(base, pos * (1.0f / 512.0f));
    float inv_freq = powf(10000.0f, -(float)j * (1.0f / 64.0f));
    float ang = (float)t * inv_freq;
    float s = sinf(ang);
    float c = cosf(ang);
    tab[(t << 6) | j] = make_float4(c * sc, s * sc, c / sc, s / sc);
}

// ---------------------------------------------------------------------------
// xPos rotate q / k in place, bf16 split layout (BH,L,DH)
// ---------------------------------------------------------------------------
__global__ __launch_bounds__(256) void xpos_apply_k(unsigned short* __restrict__ q,
                                                    unsigned short* __restrict__ k,
                                                    const float4* __restrict__ tab) {
    int g = blockIdx.x * 256 + threadIdx.x;   // 64*1024*16
    int jj = g & 15;
    int t = (g >> 4) & 1023;
    int bh = g >> 14;
    size_t off = (((size_t)((bh << 10) | t)) << 7) + jj * 8;
    ushort8v qv = *(const ushort8v*)(q + off);
    ushort8v kv = *(const ushort8v*)(k + off);
    ushort8v qo, ko;
#pragma unroll
    for (int p = 0; p < 4; ++p) {
        float4 tb = tab[(t << 6) | (jj * 4 + p)];
        float qx = bf2f(qv[2 * p]), qy = bf2f(qv[2 * p + 1]);
        float kx = bf2f(kv[2 * p]), ky = bf2f(kv[2 * p + 1]);
        qo[2 * p]     = f2bf(qx * tb.x - qy * tb.y);
        qo[2 * p + 1] = f2bf(qy * tb.x + qx * tb.y);
        ko[2 * p]     = f2bf(kx * tb.z - ky * tb.w);
        ko[2 * p + 1] = f2bf(ky * tb.z + kx * tb.w);
    }
    *(ushort8v*)(q + off) = qo;
    *(ushort8v*)(k + off) = ko;
}

// ---------------------------------------------------------------------------
// bf16 MFMA GEMM (m97 structure), used for the 4 projection GEMMs.
// MODE 0: Q proj -> bf16 split (BH,L,DH), alpha applied
// MODE 1: K proj -> bf16 split
// MODE 2: V proj -> bf16 transposed (BH,DH,L)
// MODE 4: out    -> fp32 (B,L,E)
// ---------------------------------------------------------------------------
template <int MODE>
__global__ __launch_bounds__(256)
void mm_k(const unsigned short* __restrict__ Abf, const unsigned short* __restrict__ Bp,
          const float* __restrict__ bias, void* __restrict__ Cptr, float alpha) {
    __shared__ alignas(16) unsigned short lA[128 * 32];
    __shared__ alignas(16) unsigned short lB[128 * 32];

    const int tid = threadIdx.x;
    const int lane = tid & 63;
    const int wave = tid >> 6;
    const int wr = wave >> 1, wc = wave & 1;
    const int fr = lane & 15, fq = lane >> 4;
    const int m0 = blockIdx.y * 128, n0 = blockIdx.x * 128;

    f32x4 acc[4][4];
#pragma unroll
    for (int i = 0; i < 4; ++i)
#pragma unroll
        for (int j = 0; j < 4; ++j) acc[i][j] = (f32x4){0.f, 0.f, 0.f, 0.f};

    for (int k0 = 0; k0 < 2048; k0 += 32) {
#pragma unroll
        for (int i = 0; i < 2; ++i) {
            int c = i * 256 + tid;
            int r = c >> 2, kc = c & 3;
            gload16(Abf + (size_t)(m0 + r) * 2048 + k0 + kc * 8, &lA[c * 8]);
        }
#pragma unroll
        for (int i = 0; i < 2; ++i) {
            int c = i * 256 + tid;
            int r = c >> 2, kc = c & 3;
            gload16(Bp + (size_t)(n0 + r) * 2048 + k0 + kc * 8, &lB[c * 8]);
        }
        __syncthreads();

        short8 afr[4], bfr[4];
#pragma unroll
        for (int mi = 0; mi < 4; ++mi)
            afr[mi] = *(const short8*)&lA[(wr * 64 + mi * 16 + fr) * 32 + fq * 8];
#pragma unroll
        for (int ni = 0; ni < 4; ++ni)
            bfr[ni] = *(const short8*)&lB[(wc * 64 + ni * 16 + fr) * 32 + fq * 8];
#pragma unroll
        for (int mi = 0; mi < 4; ++mi)
#pragma unroll
            for (int ni = 0; ni < 4; ++ni)
                acc[mi][ni] = __builtin_amdgcn_mfma_f32_16x16x32_bf16(
                    afr[mi], bfr[ni], acc[mi][ni], 0, 0, 0);
        __syncthreads();
    }

#pragma unroll
    for (int mi = 0; mi < 4; ++mi) {
#pragma unroll
        for (int ni = 0; ni < 4; ++ni) {
#pragma unroll
            for (int r = 0; r < 4; ++r) {
                int m = m0 + wr * 64 + mi * 16 + fq * 4 + r;
                int n = n0 + wc * 64 + ni * 16 + fr;
                float v = acc[mi][ni][r];
                if constexpr (MODE == 0 || MODE == 1) {
                    v = alpha * (v + bias[n]);
                    int b_ = m >> 10, t = m & 1023, h = n >> 7, d = n & 127;
                    unsigned short* q = (unsigned short*)Cptr;
                    q[(((size_t)(b_ * HH + h) << 10 | t) << 7) | d] = f2bf(v);
                } else if constexpr (MODE == 2) {
                    v += bias[n];
                    int b_ = m >> 10, t = m & 1023, h = n >> 7, d = n & 127;
                    unsigned short* vt = (unsigned short*)Cptr;
                    vt[((size_t)(b_ * HH + h) * 128 + d) * 1024 + t] = f2bf(v);
                } else {  // MODE 4
                    float* C = (float*)Cptr;
                    C[(size_t)m * EE + n] = v + bias[n];
                }
            }
        }
    }
}

// ---------------------------------------------------------------------------
// Fused attention: per block = one (bh, 128-row t-tile).
// Sweep 1: l[t] = sum_s exp(S-15)    (causal tiles only)
// Sweep 2: P = exp(S-15)/l -> d_out; O += P@V (bf16 MFMA via LDS relayout)
// S tiles are 128x64; LDS: Q 32K | K 16K | V 16K | P 16K = 80 KB (2 blk/CU).
// All tiles XOR-swizzled (byte ^= (row&7)<<4), sources pre-swizzled for
// global_load_lds (rule #21).
// ---------------------------------------------------------------------------
__global__ __launch_bounds__(256, 2)
void fattn_k(const unsigned short* __restrict__ qb, const unsigned short* __restrict__ kb,
             const unsigned short* __restrict__ vt, const float* __restrict__ rel,
             float* __restrict__ attnP, unsigned short* __restrict__ am) {
    __shared__ alignas(16) unsigned short smem[40960];   // 80 KB
    unsigned short* lQ = smem;            // 32 KB (reused for reductions)
    unsigned short* lK = smem + 16384;    // 16 KB
    unsigned short* lV = smem + 24576;    // 16 KB
    unsigned short* lP = smem + 32768;    // 16 KB
    float* lInv = (float*)smem;           // alias into lQ (dead after qf hoist)
    float* lRed = (float*)smem + 128;     // [2][128]

    const int tid = threadIdx.x;
    const int lane = tid & 63, wave = tid >> 6;
    const int wr = wave >> 1, wc = wave & 1;
    const int fr = lane & 15, fq = lane >> 4;

    const int bid = blockIdx.x;
    const int tt = 7 - (bid & 7);          // heavy tiles dispatched first
    const int bh = bid >> 3;
    const int hh = bh & 15, bb = bh >> 4;
    const int t0 = tt << 7;
    const int n_s = 2 * tt + 2;            // 64-wide s-tiles covering [0, t0+128)

    const unsigned short* Q = qb + ((size_t)bh << 17) + ((size_t)t0 << 7);
    const unsigned short* K = kb + ((size_t)bh << 17);
    const unsigned short* V = vt + ((size_t)bh << 17);
    const float* RL = rel + ((size_t)bh << 20) + ((size_t)t0 << 10);
    float* PO = attnP + (((size_t)(hh * BB + bb)) << 20) + ((size_t)t0 << 10);

    // ---- stage Q tile (128x128 bf16, swizzled) ----
#pragma unroll
    for (int i = 0; i < 8; ++i) {
        int o = (i * 256 + tid) * 16;
        int r = o >> 8;
        int cb = (o & 255) ^ ((r & 7) << 4);
        gload16(Q + r * 128 + (cb >> 1), (char*)lQ + o);
    }
    __syncthreads();

    // hoist q fragments: rows wr*64+mi*16+fr, K = 128 (4 ksteps)
    short8 qf[4][4];
#pragma unroll
    for (int mi = 0; mi < 4; ++mi) {
        int row = wr * 64 + mi * 16 + fr;
#pragma unroll
        for (int ks = 0; ks < 4; ++ks) {
            int cb = (ks * 64 + fq * 16) ^ ((row & 7) << 4);
            qf[mi][ks] = *(const short8*)((const char*)lQ + row * 256 + cb);
        }
    }
    __syncthreads();   // lQ dead -> lInv/lRed may be written later

    // =================== sweep 1: row sums ===================
    f32x4 l4[4];
#pragma unroll
    for (int mi = 0; mi < 4; ++mi) l4[mi] = (f32x4){0.f, 0.f, 0.f, 0.f};

    for (int j = 0; j < n_s; ++j) {
        int s0 = j << 6;
        __syncthreads();
#pragma unroll
        for (int i = 0; i < 4; ++i) {
            int o = (i * 256 + tid) * 16;
            int r = o >> 8;
            int cb = (o & 255) ^ ((r & 7) << 4);
            gload16(K + (size_t)(s0 + r) * 128 + (cb >> 1), (char*)lK + o);
        }
        __syncthreads();

        f32x4 sa[4][2];
#pragma unroll
        for (int mi = 0; mi < 4; ++mi)
#pragma unroll
            for (int ni = 0; ni < 2; ++ni) sa[mi][ni] = (f32x4){0.f, 0.f, 0.f, 0.f};
#pragma unroll
        for (int ks = 0; ks < 4; ++ks) {
            short8 bfr[2];
#pragma unroll
            for (int ni = 0; ni < 2; ++ni) {
                int row = wc * 32 + ni * 16 + fr;
                int cb = (ks * 64 + fq * 16) ^ ((row & 7) << 4);
                bfr[ni] = *(const short8*)((const char*)lK + row * 256 + cb);
            }
#pragma unroll
            for (int mi = 0; mi < 4; ++mi)
#pragma unroll
                for (int ni = 0; ni < 2; ++ni)
                    sa[mi][ni] = __builtin_amdgcn_mfma_f32_16x16x32_bf16(
                        qf[mi][ks], bfr[ni], sa[mi][ni], 0, 0, 0);
        }
#pragma unroll
        for (int mi = 0; mi < 4; ++mi) {
#pragma unroll
            for (int ni = 0; ni < 2; ++ni) {
                int s = s0 + wc * 32 + ni * 16 + fr;
#pragma unroll
                for (int r = 0; r < 4; ++r) {
                    int rowl = wr * 64 + mi * 16 + fq * 4 + r;
                    float x = sa[mi][ni][r] + RL[(size_t)rowl * 1024 + s];
                    x = (s > t0 + rowl) ? -1e9f : x;
                    l4[mi][r] += __expf(x - 15.0f);
                }
            }
        }
    }
    // reduce row sums across the 16 fr-lanes, then across wc wave pairs
#pragma unroll
    for (int mi = 0; mi < 4; ++mi) {
#pragma unroll
        for (int r = 0; r < 4; ++r) {
            float v = l4[mi][r];
            v += __shfl_xor(v, 1); v += __shfl_xor(v, 2);
            v += __shfl_xor(v, 4); v += __shfl_xor(v, 8);
            if (fr == 0) lRed[wc * 128 + wr * 64 + mi * 16 + fq * 4 + r] = v;
        }
    }
    __syncthreads();
    if (tid < 128) lInv[tid] = 1.0f / (lRed[tid] + lRed[128 + tid]);
    __syncthreads();
    f32x4 li[4];
#pragma unroll
    for (int mi = 0; mi < 4; ++mi)
#pragma unroll
        for (int r = 0; r < 4; ++r)
            li[mi][r] = lInv[wr * 64 + mi * 16 + fq * 4 + r];

    // =================== sweep 2: P write + PV ===================
    f32x4 oa[4][4];
#pragma unroll
    for (int mi = 0; mi < 4; ++mi)
#pragma unroll
        for (int ni = 0; ni < 4; ++ni) oa[mi][ni] = (f32x4){0.f, 0.f, 0.f, 0.f};

    for (int j = 0; j < n_s; ++j) {
        int s0 = j << 6;
        __syncthreads();
#pragma unroll
        for (int i = 0; i < 4; ++i) {
            int o = (i * 256 + tid) * 16;
            int r = o >> 8;
            int cb = (o & 255) ^ ((r & 7) << 4);
            gload16(K + (size_t)(s0 + r) * 128 + (cb >> 1), (char*)lK + o);
        }
#pragma unroll
        for (int i = 0; i < 4; ++i) {
            int o = (i * 256 + tid) * 16;
            int r = o >> 7;
            int cb = (o & 127) ^ ((r & 7) << 4);
            gload16(V + (size_t)r * 1024 + s0 + (cb >> 1), (char*)lV + o);
        }
        __syncthreads();

        f32x4 sa[4][2];
#pragma unroll
        for (int mi = 0; mi < 4; ++mi)
#pragma unroll
            for (int ni = 0; ni < 2; ++ni) sa[mi][ni] = (f32x4){0.f, 0.f, 0.f, 0.f};
#pragma unroll
        for (int ks = 0; ks < 4; ++ks) {
            short8 bfr[2];
#pragma unroll
            for (int ni = 0; ni < 2; ++ni) {
                int row = wc * 32 + ni * 16 + fr;
                int cb = (ks * 64 + fq * 16) ^ ((row & 7) << 4);
                bfr[ni] = *(const short8*)((const char*)lK + row * 256 + cb);
            }
#pragma unroll
            for (int mi = 0; mi < 4; ++mi)
#pragma unroll
                for (int ni = 0; ni < 2; ++ni)
                    sa[mi][ni] = __builtin_amdgcn_mfma_f32_16x16x32_bf16(
                        qf[mi][ks], bfr[ni], sa[mi][ni], 0, 0, 0);
        }
        // P = exp(S-15)/l : write fp32 to d_out, bf16 to lP (swizzled)
#pragma unroll
        for (int mi = 0; mi < 4; ++mi) {
#pragma unroll
            for (int ni = 0; ni < 2; ++ni) {
                int sl = wc * 32 + ni * 16 + fr;
                int s = s0 + sl;
#pragma unroll
                for (int r = 0; r < 4; ++r) {
                    int rowl = wr * 64 + mi * 16 + fq * 4 + r;
                    float x = sa[mi][ni][r] + RL[(size_t)rowl * 1024 + s];
                    x = (s > t0 + rowl) ? -1e9f : x;
                    float p = __expf(x - 15.0f) * li[mi][r];
                    PO[(size_t)rowl * 1024 + s] = p;
                    int cb2 = (sl * 2) ^ ((rowl & 7) << 4);
                    *(unsigned short*)((char*)lP + rowl * 128 + cb2) = f2bf(p);
                }
            }
        }
        __syncthreads();
        // PV: O[t][d] += P[t][s] * V[s][d]; A=lP rows t, B=lV rows d, K=64
#pragma unroll
        for (int ks = 0; ks < 2; ++ks) {
            short8 pf[4], vf[4];
#pragma unroll
            for (int mi = 0; mi < 4; ++mi) {
                int row = wr * 64 + mi * 16 + fr;
                int cb = (ks * 64 + fq * 16) ^ ((row & 7) << 4);
                pf[mi] = *(const short8*)((const char*)lP + row * 128 + cb);
            }
#pragma unroll
            for (int ni = 0; ni < 4; ++ni) {
                int row = wc * 64 + ni * 16 + fr;
                int cb = (ks * 64 + fq * 16) ^ ((row & 7) << 4);
                vf[ni] = *(const short8*)((const char*)lV + row * 128 + cb);
            }
#pragma unroll
            for (int mi = 0; mi < 4; ++mi)
#pragma unroll
                for (int ni = 0; ni < 4; ++ni)
                    oa[mi][ni] = __builtin_amdgcn_mfma_f32_16x16x32_bf16(
                        pf[mi], vf[ni], oa[mi][ni], 0, 0, 0);
        }
    }

    // zero-fill the strictly-upper s-range [n_s*64, 1024)
    int s_end = n_s << 6;
    int c = s_end + tid * 4;
    if (c < 1024) {
        float4 z = make_float4(0.f, 0.f, 0.f, 0.f);
        for (int rr = 0; rr < 128; ++rr)
            *(float4*)(PO + (size_t)rr * 1024 + c) = z;
    }

    // O epilogue -> am (B, L, E) bf16
#pragma unroll
    for (int mi = 0; mi < 4; ++mi)
#pragma unroll
        for (int ni = 0; ni < 4; ++ni)
#pragma unroll
            for (int r = 0; r < 4; ++r) {
                int t = t0 + wr * 64 + mi * 16 + fq * 4 + r;
                int d = wc * 64 + ni * 16 + fr;
                am[(((size_t)(bb * 1024 + t)) << 11) + hh * 128 + d] = f2bf(oa[mi][ni][r]);
            }
}

// ---------------------------------------------------------------------------
extern "C" void kernel_launch(void* const* d_in, const int* in_sizes, int n_in,
                              void* d_out, int out_size, void* d_ws, size_t ws_size,
                              hipStream_t stream) {
    const float* query = (const float*)d_in[0];
    const float* Wq    = (const float*)d_in[1];
    const float* bq    = (const float*)d_in[2];
    const float* Wk    = (const float*)d_in[3];
    const float* bk    = (const float*)d_in[4];
    const float* Wv    = (const float*)d_in[5];
    const float* bv    = (const float*)d_in[6];
    const float* Wo    = (const float*)d_in[7];
    const float* bo    = (const float*)d_in[8];
    const float* rel   = (const float*)d_in[10];

    float* out    = (float*)d_out;              // (B, L, E)
    float* attn_w = out + OUT0_ELEMS;           // (H, B, L, L)

    char* w = (char*)d_ws;
    unsigned short* Xbf = (unsigned short*)(w);               // 16MB  (B*L, E)
    unsigned short* Wqb = (unsigned short*)(w + (16 << 20));  // 8MB
    unsigned short* Wkb = (unsigned short*)(w + (24 << 20));  // 8MB
    unsigned short* Wvb = (unsigned short*)(w + (32 << 20));  // 8MB
    unsigned short* Wob = (unsigned short*)(w + (40 << 20));  // 8MB
    unsigned short* qb  = (unsigned short*)(w + (48 << 20));  // 16MB (BH,L,DH)
    unsigned short* kb  = (unsigned short*)(w + (64 << 20));  // 16MB
    unsigned short* vt  = (unsigned short*)(w + (80 << 20));  // 16MB (BH,DH,L)
    unsigned short* am  = (unsigned short*)(w + (96 << 20));  // 16MB (B,L,E)
    float4* tab         = (float4*)(w + (112 << 20));         // 1MB

    const float scaling = 0.08838834764831845f; // DH^-0.5

    xpos_table_k<<<LL, 64, 0, stream>>>(tab);

    cvt_k<<<4096, 256, 0, stream>>>(query, Xbf, OUT0_ELEMS);
    cvt_k<<<2048, 256, 0, stream>>>(Wq, Wqb, EE * EE);
    cvt_k<<<2048, 256, 0, stream>>>(Wk, Wkb, EE * EE);
    cvt_k<<<2048, 256, 0, stream>>>(Wv, Wvb, EE * EE);
    cvt_k<<<2048, 256, 0, stream>>>(Wo, Wob, EE * EE);

    dim3 gproj(EE / 128, NTOK / 128, 1);        // (16, 32)
    mm_k<0><<<gproj, 256, 0, stream>>>(Xbf, Wqb, bq, qb, scaling);
    mm_k<1><<<gproj, 256, 0, stream>>>(Xbf, Wkb, bk, kb, 1.0f);
    mm_k<2><<<gproj, 256, 0, stream>>>(Xbf, Wvb, bv, vt, 1.0f);

    xpos_apply_k<<<(NBH * LL * 16) / 256, 256, 0, stream>>>(qb, kb, tab);

    fattn_k<<<512, 256, 0, stream>>>(qb, kb, vt, rel, attn_w, am);

    dim3 gout(EE / 128, NTOK / 128, 1);         // (16, 32)
    mm_k<4><<<gout, 256, 0, stream>>>(am, Wob, bo, out, 1.0f);
}

// Round 4
// 498.824 us; speedup vs baseline: 1.6061x; 1.6061x over previous
//
#include <hip/hip_runtime.h>
#include <math.h>

// (B, L, E, H) = (4, 1024, 2048, 16), DH = 128
#define BB 4
#define LL 1024
#define EE 2048
#define HH 16
#define DHD 128
#define NTOK 4096
#define NBH 64
#define OUT0_ELEMS 8388608     // B*L*E

typedef __attribute__((ext_vector_type(8))) short short8;       // 8 bf16 (MFMA A/B frag)
typedef __attribute__((ext_vector_type(4))) float f32x4;        // MFMA C/D frag
typedef __attribute__((ext_vector_type(4))) unsigned short ushort4v;
typedef __attribute__((ext_vector_type(8))) unsigned short ushort8v;

__device__ __forceinline__ unsigned short f2bf(float x) {
    union { float f; unsigned int u; } v; v.f = x;
    unsigned int r = v.u + 0x7FFFu + ((v.u >> 16) & 1u);   // RNE
    return (unsigned short)(r >> 16);
}
__device__ __forceinline__ float bf2f(unsigned short h) {
    union { unsigned int u; float f; } v; v.u = ((unsigned int)h) << 16;
    return v.f;
}

// async global->LDS, 16B per lane
__device__ __forceinline__ void gload16(const void* g, void* l) {
    __builtin_amdgcn_global_load_lds((const __attribute__((address_space(1))) void*)g,
                                     (__attribute__((address_space(3))) void*)l,
                                     16, 0, 0);
}

// ---------------------------------------------------------------------------
// fp32 -> bf16 bulk convert
// ---------------------------------------------------------------------------
__global__ __launch_bounds__(256) void cvt_k(const float* __restrict__ in,
                                             unsigned short* __restrict__ out, int n) {
    int i = (blockIdx.x * 256 + threadIdx.x) * 8;
    if (i >= n) return;
    float4 a = *(const float4*)(in + i);
    float4 b = *(const float4*)(in + i + 4);
    ushort4v u, w;
    u.x = f2bf(a.x); u.y = f2bf(a.y); u.z = f2bf(a.z); u.w = f2bf(a.w);
    w.x = f2bf(b.x); w.y = f2bf(b.y); w.z = f2bf(b.z); w.w = f2bf(b.w);
    *(ushort4v*)(out + i) = u;
    *(ushort4v*)(out + i + 4) = w;
}

// ---------------------------------------------------------------------------
// xPos table
// ---------------------------------------------------------------------------
__global__ __launch_bounds__(64) void xpos_table_k(float4* __restrict__ tab) {
    int t = blockIdx.x;
    int j = threadIdx.x;
    float pos = (float)(t - 512);
    float base = (2.0f * (float)j + 51.2f) * (1.0f / 179.2f);
    float sc = powf(base, pos * (1.0f / 512.0f));
    float inv_freq = powf(10000.0f, -(float)j * (1.0f / 64.0f));
    float ang = (float)t * inv_freq;
    float s = sinf(ang);
    float c = cosf(ang);
    tab[(t << 6) | j] = make_float4(c * sc, s * sc, c / sc, s / sc);
}

// ---------------------------------------------------------------------------
// xPos rotate q / k in place, bf16 split layout (BH,L,DH)
// ---------------------------------------------------------------------------
__global__ __launch_bounds__(256) void xpos_apply_k(unsigned short* __restrict__ q,
                                                    unsigned short* __restrict__ k,
                                                    const float4* __restrict__ tab) {
    int g = blockIdx.x * 256 + threadIdx.x;   // 64*1024*16
    int jj = g & 15;
    int t = (g >> 4) & 1023;
    int bh = g >> 14;
    size_t off = (((size_t)((bh << 10) | t)) << 7) + jj * 8;
    ushort8v qv = *(const ushort8v*)(q + off);
    ushort8v kv = *(const ushort8v*)(k + off);
    ushort8v qo, ko;
#pragma unroll
    for (int p = 0; p < 4; ++p) {
        float4 tb = tab[(t << 6) | (jj * 4 + p)];
        float qx = bf2f(qv[2 * p]), qy = bf2f(qv[2 * p + 1]);
        float kx = bf2f(kv[2 * p]), ky = bf2f(kv[2 * p + 1]);
        qo[2 * p]     = f2bf(qx * tb.x - qy * tb.y);
        qo[2 * p + 1] = f2bf(qy * tb.x + qx * tb.y);
        ko[2 * p]     = f2bf(kx * tb.z - ky * tb.w);
        ko[2 * p + 1] = f2bf(ky * tb.z + kx * tb.w);
    }
    *(ushort8v*)(q + off) = qo;
    *(ushort8v*)(k + off) = ko;
}

// ---------------------------------------------------------------------------
// bf16 MFMA GEMM (m97 structure), the 4 projection GEMMs.
// MODE 0: Q proj -> bf16 split (BH,L,DH), alpha applied
// MODE 1: K proj -> bf16 split
// MODE 2: V proj -> bf16 transposed (BH,DH,L)
// MODE 4: out    -> fp32 (B,L,E)
// ---------------------------------------------------------------------------
template <int MODE>
__global__ __launch_bounds__(256)
void mm_k(const unsigned short* __restrict__ Abf, const unsigned short* __restrict__ Bp,
          const float* __restrict__ bias, void* __restrict__ Cptr, float alpha) {
    __shared__ alignas(16) unsigned short lA[128 * 32];
    __shared__ alignas(16) unsigned short lB[128 * 32];

    const int tid = threadIdx.x;
    const int lane = tid & 63;
    const int wave = tid >> 6;
    const int wr = wave >> 1, wc = wave & 1;
    const int fr = lane & 15, fq = lane >> 4;
    const int m0 = blockIdx.y * 128, n0 = blockIdx.x * 128;

    f32x4 acc[4][4];
#pragma unroll
    for (int i = 0; i < 4; ++i)
#pragma unroll
        for (int j = 0; j < 4; ++j) acc[i][j] = (f32x4){0.f, 0.f, 0.f, 0.f};

    for (int k0 = 0; k0 < 2048; k0 += 32) {
#pragma unroll
        for (int i = 0; i < 2; ++i) {
            int c = i * 256 + tid;
            int r = c >> 2, kc = c & 3;
            gload16(Abf + (size_t)(m0 + r) * 2048 + k0 + kc * 8, &lA[c * 8]);
        }
#pragma unroll
        for (int i = 0; i < 2; ++i) {
            int c = i * 256 + tid;
            int r = c >> 2, kc = c & 3;
            gload16(Bp + (size_t)(n0 + r) * 2048 + k0 + kc * 8, &lB[c * 8]);
        }
        __syncthreads();

        short8 afr[4], bfr[4];
#pragma unroll
        for (int mi = 0; mi < 4; ++mi)
            afr[mi] = *(const short8*)&lA[(wr * 64 + mi * 16 + fr) * 32 + fq * 8];
#pragma unroll
        for (int ni = 0; ni < 4; ++ni)
            bfr[ni] = *(const short8*)&lB[(wc * 64 + ni * 16 + fr) * 32 + fq * 8];
#pragma unroll
        for (int mi = 0; mi < 4; ++mi)
#pragma unroll
            for (int ni = 0; ni < 4; ++ni)
                acc[mi][ni] = __builtin_amdgcn_mfma_f32_16x16x32_bf16(
                    afr[mi], bfr[ni], acc[mi][ni], 0, 0, 0);
        __syncthreads();
    }

#pragma unroll
    for (int mi = 0; mi < 4; ++mi) {
#pragma unroll
        for (int ni = 0; ni < 4; ++ni) {
#pragma unroll
            for (int r = 0; r < 4; ++r) {
                int m = m0 + wr * 64 + mi * 16 + fq * 4 + r;
                int n = n0 + wc * 64 + ni * 16 + fr;
                float v = acc[mi][ni][r];
                if constexpr (MODE == 0 || MODE == 1) {
                    v = alpha * (v + bias[n]);
                    int b_ = m >> 10, t = m & 1023, h = n >> 7, d = n & 127;
                    unsigned short* q = (unsigned short*)Cptr;
                    q[(((size_t)(b_ * HH + h) << 10 | t) << 7) | d] = f2bf(v);
                } else if constexpr (MODE == 2) {
                    v += bias[n];
                    int b_ = m >> 10, t = m & 1023, h = n >> 7, d = n & 127;
                    unsigned short* vt = (unsigned short*)Cptr;
                    vt[((size_t)(b_ * HH + h) * 128 + d) * 1024 + t] = f2bf(v);
                } else {  // MODE 4
                    float* C = (float*)Cptr;
                    C[(size_t)m * EE + n] = v + bias[n];
                }
            }
        }
    }
}

// ---------------------------------------------------------------------------
// scores_k: one block per causal 128x128 tile (t-tile tt, s-tile ss<=tt, bh).
// S = q@k^T (K=128 MFMA), then slab-transposed epilogue:
//   e = exp(S + rel - 15)   (causal-masked on diagonal tiles)
// e written fp32 (unnormalized) into the attn region of d_out; per-row
// partial sums into psum[bh][t][ss]. All global epilogue I/O is float4.
// ---------------------------------------------------------------------------
__global__ __launch_bounds__(256)
void scores_k(const unsigned short* __restrict__ qb, const unsigned short* __restrict__ kb,
              const float* __restrict__ rel, float* __restrict__ attnP,
              float* __restrict__ psum) {
    __shared__ alignas(16) char smem[16384];
    unsigned short* lA = (unsigned short*)smem;           // 128x32 bf16
    unsigned short* lB = (unsigned short*)(smem + 8192);  // 128x32 bf16
    float* slab = (float*)smem;                           // 32x128 f32 (epilogue reuse)

    const int tid = threadIdx.x;
    const int lane = tid & 63, wave = tid >> 6;
    const int wr = wave >> 1, wc = wave & 1;
    const int fr = lane & 15, fq = lane >> 4;

    int idx = blockIdx.x;                  // 0..35 triangular
    int tt = (int)((sqrtf(8.f * (float)idx + 1.f) - 1.f) * 0.5f);
    while ((tt + 1) * (tt + 2) / 2 <= idx) ++tt;
    while (tt * (tt + 1) / 2 > idx) --tt;
    const int ss = idx - tt * (tt + 1) / 2;
    const int t0 = tt << 7, s0 = ss << 7;
    const int bh = blockIdx.y;
    const int hh = bh & 15, bb = bh >> 4;

    const unsigned short* Q = qb + ((size_t)bh << 17);
    const unsigned short* K = kb + ((size_t)bh << 17);

    f32x4 acc[4][4];
#pragma unroll
    for (int i = 0; i < 4; ++i)
#pragma unroll
        for (int j = 0; j < 4; ++j) acc[i][j] = (f32x4){0.f, 0.f, 0.f, 0.f};

    for (int k0 = 0; k0 < 128; k0 += 32) {
#pragma unroll
        for (int i = 0; i < 2; ++i) {
            int c = i * 256 + tid;
            int r = c >> 2, kc = c & 3;
            gload16(Q + (size_t)(t0 + r) * 128 + k0 + kc * 8, &lA[c * 8]);
        }
#pragma unroll
        for (int i = 0; i < 2; ++i) {
            int c = i * 256 + tid;
            int r = c >> 2, kc = c & 3;
            gload16(K + (size_t)(s0 + r) * 128 + k0 + kc * 8, &lB[c * 8]);
        }
        __syncthreads();

        short8 afr[4], bfr[4];
#pragma unroll
        for (int mi = 0; mi < 4; ++mi)
            afr[mi] = *(const short8*)&lA[(wr * 64 + mi * 16 + fr) * 32 + fq * 8];
#pragma unroll
        for (int ni = 0; ni < 4; ++ni)
            bfr[ni] = *(const short8*)&lB[(wc * 64 + ni * 16 + fr) * 32 + fq * 8];
#pragma unroll
        for (int mi = 0; mi < 4; ++mi)
#pragma unroll
            for (int ni = 0; ni < 4; ++ni)
                acc[mi][ni] = __builtin_amdgcn_mfma_f32_16x16x32_bf16(
                    afr[mi], bfr[ni], acc[mi][ni], 0, 0, 0);
        __syncthreads();
    }

    // ---- slab-transposed epilogue: 4 slabs of 32 rows ----
    float* PO = attnP + (((size_t)(hh * BB + bb)) << 20);
    const float* RLb = rel + ((size_t)bh << 20);
#pragma unroll
    for (int sl = 0; sl < 4; ++sl) {
        if (wr == (sl >> 1)) {
#pragma unroll
            for (int mi2 = 0; mi2 < 2; ++mi2) {
                int mi = ((sl & 1) << 1) + mi2;
#pragma unroll
                for (int ni = 0; ni < 4; ++ni)
#pragma unroll
                    for (int r = 0; r < 4; ++r) {
                        int srow = (mi2 << 4) + (fq << 2) + r;
                        int col = (wc << 6) + (ni << 4) + fr;
                        slab[srow * 128 + (col ^ (((srow >> 2) & 3) << 4))] = acc[mi][ni][r];
                    }
            }
        }
        __syncthreads();
        {
            int srow = tid >> 3;
            int tg = t0 + (sl << 5) + srow;
            const float* RL = RLb + ((size_t)tg << 10) + s0;
            float* PR = PO + ((size_t)tg << 10) + s0;
            float rsum = 0.f;
#pragma unroll
            for (int c = 0; c < 4; ++c) {
                int col = ((tid & 7) << 2) + (c << 5);   // 8 lanes cover 128B contiguous
                float4 sv = *(const float4*)&slab[srow * 128 + (col ^ (((srow >> 2) & 3) << 4))];
                float4 rl = *(const float4*)(RL + col);
                float4 e;
                e.x = (s0 + col     <= tg) ? __expf(sv.x + rl.x - 15.f) : 0.f;
                e.y = (s0 + col + 1 <= tg) ? __expf(sv.y + rl.y - 15.f) : 0.f;
                e.z = (s0 + col + 2 <= tg) ? __expf(sv.z + rl.z - 15.f) : 0.f;
                e.w = (s0 + col + 3 <= tg) ? __expf(sv.w + rl.w - 15.f) : 0.f;
                *(float4*)(PR + col) = e;
                rsum += e.x + e.y + e.z + e.w;
            }
            rsum += __shfl_xor(rsum, 1);
            rsum += __shfl_xor(rsum, 2);
            rsum += __shfl_xor(rsum, 4);
            if ((tid & 7) == 0)
                psum[((((size_t)bh << 10) + tg) << 3) + ss] = rsum;
        }
        __syncthreads();
    }
}

// ---------------------------------------------------------------------------
// pv_k: per (t-tile, bh): O = P~ @ V  (K bounded by causality), then O/l.
// P~ read fp32 from d_out attn region, reg-converted to bf16 LDS.
// ---------------------------------------------------------------------------
__global__ __launch_bounds__(256)
void pv_k(const float* __restrict__ attnP, const unsigned short* __restrict__ vt,
          const float* __restrict__ psum, unsigned short* __restrict__ am) {
    __shared__ alignas(16) unsigned short lA[128 * 32];
    __shared__ alignas(16) unsigned short lB[128 * 32];
    __shared__ float lInv[128];

    const int tid = threadIdx.x;
    const int lane = tid & 63, wave = tid >> 6;
    const int wr = wave >> 1, wc = wave & 1;
    const int fr = lane & 15, fq = lane >> 4;
    const int tt = 7 - blockIdx.x;       // heavy first
    const int t0 = tt << 7;
    const int bh = blockIdx.y;
    const int hh = bh & 15, bb = bh >> 4;

    const float* PO = attnP + (((size_t)(hh * BB + bb)) << 20) + ((size_t)t0 << 10);
    const unsigned short* Vb = vt + ((size_t)bh << 17);

    if (tid < 128) {
        const float* p = psum + ((((size_t)bh << 10) + t0 + tid) << 3);
        float s = 0.f;
#pragma unroll
        for (int j = 0; j < 8; ++j) s += (j <= tt) ? p[j] : 0.f;
        lInv[tid] = 1.f / s;
    }

    f32x4 acc[4][4];
#pragma unroll
    for (int i = 0; i < 4; ++i)
#pragma unroll
        for (int j = 0; j < 4; ++j) acc[i][j] = (f32x4){0.f, 0.f, 0.f, 0.f};

    const int kend = (tt + 1) << 7;
    for (int k0 = 0; k0 < kend; k0 += 32) {
#pragma unroll
        for (int i = 0; i < 4; ++i) {            // stage P~ 128x32 fp32 -> bf16
            int c = i * 256 + tid;
            int r = c >> 3, cc = c & 7;
            float4 v = *(const float4*)(PO + (size_t)r * 1024 + k0 + cc * 4);
            ushort4v h;
            h.x = f2bf(v.x); h.y = f2bf(v.y); h.z = f2bf(v.z); h.w = f2bf(v.w);
            *(ushort4v*)&lA[r * 32 + cc * 4] = h;
        }
#pragma unroll
        for (int i = 0; i < 2; ++i) {            // stage V^T 128x32
            int c = i * 256 + tid;
            int r = c >> 2, kc = c & 3;
            gload16(Vb + (size_t)r * 1024 + k0 + kc * 8, &lB[c * 8]);
        }
        __syncthreads();

        short8 afr[4], bfr[4];
#pragma unroll
        for (int mi = 0; mi < 4; ++mi)
            afr[mi] = *(const short8*)&lA[(wr * 64 + mi * 16 + fr) * 32 + fq * 8];
#pragma unroll
        for (int ni = 0; ni < 4; ++ni)
            bfr[ni] = *(const short8*)&lB[(wc * 64 + ni * 16 + fr) * 32 + fq * 8];
#pragma unroll
        for (int mi = 0; mi < 4; ++mi)
#pragma unroll
            for (int ni = 0; ni < 4; ++ni)
                acc[mi][ni] = __builtin_amdgcn_mfma_f32_16x16x32_bf16(
                    afr[mi], bfr[ni], acc[mi][ni], 0, 0, 0);
        __syncthreads();
    }

#pragma unroll
    for (int mi = 0; mi < 4; ++mi)
#pragma unroll
        for (int ni = 0; ni < 4; ++ni)
#pragma unroll
            for (int r = 0; r < 4; ++r) {
                int tl = wr * 64 + mi * 16 + fq * 4 + r;
                int d = wc * 64 + ni * 16 + fr;
                float o = acc[mi][ni][r] * lInv[tl];
                am[(((size_t)(bb * 1024 + t0 + tl)) << 11) + hh * 128 + d] = f2bf(o);
            }
}

// ---------------------------------------------------------------------------
// norm_k: in-place normalize attn rows (causal part) + zero-fill upper part.
// One wave per row, all float4.
// ---------------------------------------------------------------------------
__global__ __launch_bounds__(256)
void norm_k(float* __restrict__ attnP, const float* __restrict__ psum) {
    const int tid = threadIdx.x;
    const int lane = tid & 63, wave = tid >> 6;
    const int row = blockIdx.x * 4 + wave;       // (bh<<10)|t
    const int bh = row >> 10, t = row & 1023;
    const int hh = bh & 15, bb = bh >> 4;
    const int tt = t >> 7;
    float v = (lane < 8 && lane <= tt) ? psum[((size_t)row << 3) + lane] : 0.f;
    v += __shfl_xor(v, 1);
    v += __shfl_xor(v, 2);
    v += __shfl_xor(v, 4);
    float inv = 1.f / __shfl(v, 0);
    float* PR = attnP + (((size_t)(hh * BB + bb)) << 20) + ((size_t)t << 10);
#pragma unroll
    for (int it = 0; it < 4; ++it) {
        int col = it * 256 + lane * 4;
        if (col <= t) {
            float4 x = *(const float4*)(PR + col);
            x.x *= inv; x.y *= inv; x.z *= inv; x.w *= inv;
            *(float4*)(PR + col) = x;            // masked elems are 0 already
        } else {
            *(float4*)(PR + col) = make_float4(0.f, 0.f, 0.f, 0.f);
        }
    }
}

// ---------------------------------------------------------------------------
extern "C" void kernel_launch(void* const* d_in, const int* in_sizes, int n_in,
                              void* d_out, int out_size, void* d_ws, size_t ws_size,
                              hipStream_t stream) {
    const float* query = (const float*)d_in[0];
    const float* Wq    = (const float*)d_in[1];
    const float* bq    = (const float*)d_in[2];
    const float* Wk    = (const float*)d_in[3];
    const float* bk    = (const float*)d_in[4];
    const float* Wv    = (const float*)d_in[5];
    const float* bv    = (const float*)d_in[6];
    const float* Wo    = (const float*)d_in[7];
    const float* bo    = (const float*)d_in[8];
    const float* rel   = (const float*)d_in[10];

    float* out    = (float*)d_out;              // (B, L, E)
    float* attn_w = out + OUT0_ELEMS;           // (H, B, L, L)

    char* w = (char*)d_ws;
    unsigned short* Xbf = (unsigned short*)(w);               // 16MB  (B*L, E)
    unsigned short* Wqb = (unsigned short*)(w + (16 << 20));  // 8MB
    unsigned short* Wkb = (unsigned short*)(w + (24 << 20));  // 8MB
    unsigned short* Wvb = (unsigned short*)(w + (32 << 20));  // 8MB
    unsigned short* Wob = (unsigned short*)(w + (40 << 20));  // 8MB
    unsigned short* qb  = (unsigned short*)(w + (48 << 20));  // 16MB (BH,L,DH)
    unsigned short* kb  = (unsigned short*)(w + (64 << 20));  // 16MB
    unsigned short* vt  = (unsigned short*)(w + (80 << 20));  // 16MB (BH,DH,L)
    unsigned short* am  = (unsigned short*)(w + (96 << 20));  // 16MB (B,L,E)
    float4* tab         = (float4*)(w + (112 << 20));         // 1MB
    float* psum         = (float*)(w + (113u << 20));         // 2MB (BH,L,8)

    const float scaling = 0.08838834764831845f; // DH^-0.5

    xpos_table_k<<<LL, 64, 0, stream>>>(tab);

    cvt_k<<<4096, 256, 0, stream>>>(query, Xbf, OUT0_ELEMS);
    cvt_k<<<2048, 256, 0, stream>>>(Wq, Wqb, EE * EE);
    cvt_k<<<2048, 256, 0, stream>>>(Wk, Wkb, EE * EE);
    cvt_k<<<2048, 256, 0, stream>>>(Wv, Wvb, EE * EE);
    cvt_k<<<2048, 256, 0, stream>>>(Wo, Wob, EE * EE);

    dim3 gproj(EE / 128, NTOK / 128, 1);        // (16, 32)
    mm_k<0><<<gproj, 256, 0, stream>>>(Xbf, Wqb, bq, qb, scaling);
    mm_k<1><<<gproj, 256, 0, stream>>>(Xbf, Wkb, bk, kb, 1.0f);
    mm_k<2><<<gproj, 256, 0, stream>>>(Xbf, Wvb, bv, vt, 1.0f);

    xpos_apply_k<<<(NBH * LL * 16) / 256, 256, 0, stream>>>(qb, kb, tab);

    dim3 gsc(36, NBH);                          // causal tiles only
    scores_k<<<gsc, 256, 0, stream>>>(qb, kb, rel, attn_w, psum);

    dim3 gpv(8, NBH);
    pv_k<<<gpv, 256, 0, stream>>>(attn_w, vt, psum, am);

    norm_k<<<NBH * LL / 4, 256, 0, stream>>>(attn_w, psum);

    dim3 gout(EE / 128, NTOK / 128, 1);         // (16, 32)
    mm_k<4><<<gout, 256, 0, stream>>>(am, Wob, bo, out, 1.0f);
}